// Round 8
// baseline (147.648 us; speedup 1.0000x reference)
//
#include <hip/hip_runtime.h>
#include <stdint.h>

typedef _Float16 f16;
typedef __attribute__((ext_vector_type(4))) _Float16 f16x4;
typedef __attribute__((ext_vector_type(8))) _Float16 f16x8;
typedef __attribute__((ext_vector_type(4))) float f32x4;
typedef __attribute__((ext_vector_type(2))) float fv2;
typedef __attribute__((ext_vector_type(4))) float fv4;

#define H0 64
#define W0 128
#define NPIX 8192   // H0*W0
#define KD 256
#define NCAT 10880  // 8192 + 2048 + 512 + 128
#define OFF1 8192
#define OFF2 10240
#define OFF3 10752

// ---------------------------------------------------------------------------
// 1) fused pre-pass: transpose+cvt both fmaps, pooled feature rows (read
//    directly from fp32 input -> no cross-block dep), window metadata.
//    grid = 512 (f1 transpose) + 512 (f2) + 336 (pool) + 32 (meta) = 1392
// ---------------------------------------------------------------------------
__global__ __launch_bounds__(256) void fused_pre(const float* __restrict__ in0,
                                                 const float* __restrict__ in1,
                                                 const float* __restrict__ coords,
                                                 f16* __restrict__ A,
                                                 f16* __restrict__ Bc,
                                                 int2* __restrict__ meta) {
  __shared__ f16 tile[64][65];
  int bid = blockIdx.x;
  int t = threadIdx.x;

  if (bid < 1024) {                       // ---- transpose + cvt ----
    const float* in = (bid < 512) ? in0 : in1;
    f16* out = (bid < 512) ? A : Bc;
    int bx = bid & 511;
    int m0 = (bx & 127) * 64;
    int d0 = (bx >> 7) * 64;
    int a = t & 63, b = t >> 6;
#pragma unroll
    for (int i = 0; i < 16; ++i) {
      int d = b + i * 4;
      tile[a][d] = (f16)in[(size_t)(d0 + d) * NPIX + m0 + a];
    }
    __syncthreads();
#pragma unroll
    for (int i = 0; i < 16; ++i) {
      int m = b + i * 4;
      out[(size_t)(m0 + m) * KD + d0 + a] = tile[m][a];
    }
  } else if (bid < 1360) {                // ---- pooled feature rows ----
    int idx = (bid - 1024) * 256 + t;     // 0..86015
    float acc[8] = {0, 0, 0, 0, 0, 0, 0, 0};
    int r, dc;
    if (idx < 65536) {                    // lev1: 2048 rows, 2x2
      int r1 = idx & 2047; dc = idx >> 11; r = r1;
      int y = r1 >> 6, x = r1 & 63;
#pragma unroll
      for (int e = 0; e < 8; ++e) {
        const float* p = in1 + (size_t)(dc * 8 + e) * NPIX + (y * 2) * W0 + x * 2;
        fv2 s0 = *(const fv2*)p;
        fv2 s1 = *(const fv2*)(p + W0);
        acc[e] = (s0[0] + s0[1] + s1[0] + s1[1]) * 0.25f;
      }
    } else if (idx < 81920) {             // lev2: 512 rows, 4x4
      int i2 = idx - 65536;
      int r2 = i2 & 511; dc = i2 >> 9; r = 2048 + r2;
      int y = r2 >> 5, x = r2 & 31;
#pragma unroll
      for (int e = 0; e < 8; ++e) {
        const float* p = in1 + (size_t)(dc * 8 + e) * NPIX + (y * 4) * W0 + x * 4;
        float s = 0.f;
#pragma unroll
        for (int h = 0; h < 4; ++h) {
          fv4 v = *(const fv4*)(p + h * W0);
          s += v[0] + v[1] + v[2] + v[3];
        }
        acc[e] = s * 0.0625f;
      }
    } else {                              // lev3: 128 rows, 8x8
      int i3 = idx - 81920;
      int r3 = i3 & 127; dc = i3 >> 7; r = 2560 + r3;
      int y = r3 >> 4, x = r3 & 15;
#pragma unroll
      for (int e = 0; e < 8; ++e) {
        const float* p = in1 + (size_t)(dc * 8 + e) * NPIX + (y * 8) * W0 + x * 8;
        float s = 0.f;
#pragma unroll
        for (int h = 0; h < 8; ++h) {
          fv4 v0 = *(const fv4*)(p + h * W0);
          fv4 v1 = *(const fv4*)(p + h * W0 + 4);
          s += v0[0] + v0[1] + v0[2] + v0[3] + v1[0] + v1[1] + v1[2] + v1[3];
        }
        acc[e] = s * 0.015625f;
      }
    }
    f16x8 o;
#pragma unroll
    for (int e = 0; e < 8; ++e) o[e] = (f16)acc[e];
    *(f16x8*)(Bc + (size_t)(8192 + r) * KD + dc * 8) = o;
  } else {                                // ---- window metadata ----
    int m = (bid - 1360) * 256 + t;
    float cx = coords[m];
    float cy = coords[NPIX + m];
    int mx = 0, my = 0;
#pragma unroll
    for (int lev = 0; lev < 4; ++lev) {
      float inv = 1.0f / (float)(1 << lev);
      int X0 = (int)floorf(cx * inv) - 4;   // identical expr in corr_sample
      int Y0 = (int)floorf(cy * inv) - 4;
      mx |= (X0 & 0xff) << (8 * lev);
      my |= (Y0 & 0xff) << (8 * lev);
    }
    meta[m] = make_int2(mx, my);
  }
}

// ---------------------------------------------------------------------------
// 2) GEMM: A-in-registers, B-only LDS. Block = 256 thr (4 waves 2x2),
//    bm-tile 128, processes G=5 bn-tiles of 128 over the same A-regs.
//    Wave holds A rows (64 x K=256) in 128 VGPRs; B double-buffered in
//    32 KB LDS (BK=64, XOR-swizzled, 0-conflict scheme from r5); counted
//    vmcnt(4); compact-window scatter epilogue with row early-out.
// ---------------------------------------------------------------------------
#define GLD16(gp, lp)                                                          \
  __builtin_amdgcn_global_load_lds(                                            \
      (const __attribute__((address_space(1))) void*)(gp),                     \
      (__attribute__((address_space(3))) void*)(lp), 16, 0, 0)

__global__ __launch_bounds__(256, 2) void corr_gemm(const f16* __restrict__ A,
                                                    const f16* __restrict__ B,
                                                    const int2* __restrict__ meta,
                                                    f16* __restrict__ Wbuf) {
  __shared__ f16 lds[16384];   // 2 bufs x (128 cols x 64 k) = 32 KB

  int bid = blockIdx.x;        // 1088 = 8 xcd * 8 bm * 17 grp
  // XCD x owns bm-tiles [x*8, x*8+8): per-XCD A set = 512 KB, L2-resident.
  int bm = ((((bid & 7) << 3) | ((bid >> 3) & 7))) << 7;
  int grp = bid >> 6;          // 0..16
  int bn0 = grp * 640;

  int t = threadIdx.x;
  int lane = t & 63;
  int w = t >> 6;
  int rg = w >> 1;             // row-group (64 rows)
  int cg = w & 1;              // col-group (64 cols)
  int lr = lane & 15;
  int ko = lane >> 4;

  // ---- A into registers: rows bm + rg*64 + i*16 + lr, full K ----
  f16x8 af[8][4];              // 128 VGPRs
  {
    const f16* Ar = A + (size_t)(bm + rg * 64 + lr) * KD + ko * 8;
#pragma unroll
    for (int kk = 0; kk < 8; ++kk)
#pragma unroll
      for (int i = 0; i < 4; ++i)
        af[kk][i] = *(const f16x8*)(Ar + (size_t)(i * 16) * KD + kk * 32);
  }

  // B read byte-offsets within an 8KB kk-half (2 cols/128B line, XOR swizzle)
  int offB[4];
#pragma unroll
  for (int i = 0; i < 4; ++i) {
    int col = cg * 64 + i * 16 + lr;
    int line = col >> 1;
    int phys = (((col & 1) << 2) | ko) ^ (line & 7);
    offB[i] = line * 128 + phys * 16;
  }

  // staging source terms: linear LDS chunk c=i*256+t -> inverse-swizzled global
  int coloff[4];
#pragma unroll
  for (int i = 0; i < 4; ++i) {
    int c = i * 256 + t;
    int half = c >> 9;
    int ch = c & 511;
    int line = ch >> 3;
    int lg = (ch & 7) ^ (line & 7);
    coloff[i] = (line * 2 + (lg >> 2)) * KD + half * 32 + (lg & 3) * 8;
  }
  const f16* Bg = B + (size_t)bn0 * KD;

#define STAGE(bufi, s)                                                         \
  do {                                                                         \
    f16* d = lds + (bufi) * 8192;                                              \
    const f16* sp = Bg + (size_t)((s) >> 2) * (128 * KD) + ((s) & 3) * 64;     \
    GLD16(sp + coloff[0], d + t * 8);                                          \
    GLD16(sp + coloff[1], d + 2048 + t * 8);                                   \
    GLD16(sp + coloff[2], d + 4096 + t * 8);                                   \
    GLD16(sp + coloff[3], d + 6144 + t * 8);                                   \
  } while (0)

  f32x4 acc[4][4];
#pragma unroll
  for (int i = 0; i < 4; ++i)
#pragma unroll
    for (int j = 0; j < 4; ++j) acc[i][j] = (f32x4){0.f, 0.f, 0.f, 0.f};

  STAGE(0, 0);
  STAGE(1, 1);
  asm volatile("s_waitcnt vmcnt(4)" ::: "memory");  // A-loads + stage0 landed
  __builtin_amdgcn_s_barrier();

  for (int g = 0; g < 5; ++g) {
#pragma unroll
    for (int ks = 0; ks < 4; ++ks) {
      const int s = g * 4 + ks;
      const char* bb = (const char*)lds + (size_t)((s & 1) * 16384);
      f16x8 bf0[4], bf1[4];
#pragma unroll
      for (int i = 0; i < 4; ++i) bf0[i] = *(const f16x8*)(bb + offB[i]);
      asm volatile("s_waitcnt lgkmcnt(0)" ::: "memory");
      __builtin_amdgcn_sched_barrier(0);
#pragma unroll
      for (int i = 0; i < 4; ++i) bf1[i] = *(const f16x8*)(bb + 8192 + offB[i]);
      __builtin_amdgcn_s_setprio(1);
#pragma unroll
      for (int mi = 0; mi < 4; ++mi)
#pragma unroll
        for (int ni = 0; ni < 4; ++ni)
          acc[mi][ni] = __builtin_amdgcn_mfma_f32_16x16x32_f16(
              af[ks * 2][mi], bf0[ni], acc[mi][ni], 0, 0, 0);
      __builtin_amdgcn_s_setprio(0);
      asm volatile("s_waitcnt lgkmcnt(0)" ::: "memory");
      __builtin_amdgcn_sched_barrier(0);
      __builtin_amdgcn_s_setprio(1);
#pragma unroll
      for (int mi = 0; mi < 4; ++mi)
#pragma unroll
        for (int ni = 0; ni < 4; ++ni)
          acc[mi][ni] = __builtin_amdgcn_mfma_f32_16x16x32_f16(
              af[ks * 2 + 1][mi], bf1[ni], acc[mi][ni], 0, 0, 0);
      __builtin_amdgcn_s_setprio(0);
      __builtin_amdgcn_s_barrier();                // all waves done with buf
      if (s < 18) {
        STAGE(s & 1, s + 2);
        asm volatile("s_waitcnt vmcnt(4)" ::: "memory");  // stage s+1 landed
      } else if (s == 18) {
        asm volatile("s_waitcnt vmcnt(0)" ::: "memory");
      }
      __builtin_amdgcn_s_barrier();                // next buf visible
    }

    // ---- compact-window scatter epilogue for bn-tile g ----
    {
      int bn_t = bn0 + g * 128;
      int lev, n0, wlog;
      if (bn_t < OFF1)      { lev = 0; n0 = bn_t;        wlog = 7; }
      else if (bn_t < OFF2) { lev = 1; n0 = bn_t - OFF1; wlog = 6; }
      else if (bn_t < OFF3) { lev = 2; n0 = bn_t - OFF2; wlog = 5; }
      else                  { lev = 3; n0 = bn_t - OFF3; wlog = 4; }
      int wmask = (1 << wlog) - 1;
      int yA = n0 >> wlog;
      int yB = (n0 + 127) >> wlog;
      int ycol[4], xcol[4];
#pragma unroll
      for (int ni = 0; ni < 4; ++ni) {
        int n = n0 + cg * 64 + ni * 16 + lr;
        ycol[ni] = n >> wlog;
        xcol[ni] = n & wmask;
      }
      f16* wlev = Wbuf + (size_t)(lev * 100) * NPIX;
      int sh = lev * 8;
#pragma unroll
      for (int mi = 0; mi < 4; ++mi)
#pragma unroll
        for (int r2 = 0; r2 < 4; ++r2) {
          int grow = bm + rg * 64 + mi * 16 + ko * 4 + r2;
          int2 mv = meta[grow];
          int Y0 = (int)(signed char)((mv.y >> sh) & 0xff);
          if (Y0 <= yB && Y0 + 9 >= yA) {
            int X0 = (int)(signed char)((mv.x >> sh) & 0xff);
            f16* rowp = wlev + grow;
#pragma unroll
            for (int ni = 0; ni < 4; ++ni) {
              int dy = ycol[ni] - Y0;
              int dx = xcol[ni] - X0;
              if ((unsigned)dy < 10u && (unsigned)dx < 10u)
                rowp[(size_t)(dy * 10 + dx) * NPIX] =
                    (f16)(acc[mi][ni][r2] * 0.0625f);
            }
          }
        }
#pragma unroll
      for (int mi = 0; mi < 4; ++mi)
#pragma unroll
        for (int ni = 0; ni < 4; ++ni)
          acc[mi][ni] = (f32x4){0.f, 0.f, 0.f, 0.f};
    }
  }
#undef STAGE
}

// ---------------------------------------------------------------------------
// 3) bilinear sampling from compact corner buffer W[lev*100+dy*10+dx][m].
// ---------------------------------------------------------------------------
__global__ __launch_bounds__(256) void corr_sample(const f16* __restrict__ Wbuf,
                                                   const float* __restrict__ coords,
                                                   float* __restrict__ out) {
  int bx = blockIdx.x;            // 288 = 8 xcd * 36
  int xcd = bx & 7;
  int idx = bx >> 3;              // 0..35
  int j = idx % 9;                // window row
  int mc = xcd + 8 * (idx / 9);   // m-chunk 0..31
  int m = mc * 256 + threadIdx.x;
  int lev = blockIdx.z;
  int Hl = H0 >> lev, Wl = W0 >> lev;

  float cx = coords[m];
  float cy = coords[NPIX + m];
  float inv = 1.0f / (float)(1 << lev);
  float xb = cx * inv, yb = cy * inv;
  float fx = floorf(xb), fy = floorf(yb);
  int X0 = (int)fx - 4, Y0 = (int)fy - 4;   // matches fused_pre meta exactly
  float wx1 = xb - fx, wx0 = 1.0f - wx1;
  float wy1 = yb - fy, wy0 = 1.0f - wy1;

  const f16* wb = Wbuf + (size_t)(lev * 100) * NPIX + m;
  float* op = out + ((size_t)lev * 81 + (size_t)j * 9) * NPIX + m;

  float cur[10], nxt[10];
  auto loadrow = [&](float* row, int jr) {
    int y = Y0 + jr;
    bool yin = (unsigned)y < (unsigned)Hl;
#pragma unroll
    for (int i = 0; i < 10; ++i) {
      int x = X0 + i;
      bool in = yin && ((unsigned)x < (unsigned)Wl);
      row[i] = in ? (float)wb[(size_t)(jr * 10 + i) * NPIX] : 0.0f;
    }
  };
  loadrow(cur, j);
  loadrow(nxt, j + 1);
#pragma unroll
  for (int i = 0; i < 9; ++i) {
    float v = wy0 * (wx0 * cur[i] + wx1 * cur[i + 1])
            + wy1 * (wx0 * nxt[i] + wx1 * nxt[i + 1]);
    op[(size_t)i * NPIX] = v;
  }
}

// ---------------------------------------------------------------------------
extern "C" void kernel_launch(void* const* d_in, const int* in_sizes, int n_in,
                              void* d_out, int out_size, void* d_ws, size_t ws_size,
                              hipStream_t stream) {
  const float* fmap1  = (const float*)d_in[0];   // [1,256,64,128]
  const float* fmap2  = (const float*)d_in[1];
  const float* coords = (const float*)d_in[2];   // [1,2,64,128]
  float* out = (float*)d_out;                    // [1,324,64,128] fp32

  char* ws = (char*)d_ws;
  size_t offA = 0;
  size_t offB = offA + (size_t)NPIX * KD * 2;    // A: 4 MB
  size_t offW = offB + (size_t)NCAT * KD * 2;    // B: 5.44 MB
  size_t offM = offW + (size_t)400 * NPIX * 2;   // W: 6.55 MB
  size_t need = offM + (size_t)NPIX * 8;         // meta: 64 KB => ~16.1 MB
  if (ws_size < need) return;

  f16*  A    = (f16*)(ws + offA);
  f16*  Bc   = (f16*)(ws + offB);
  f16*  Wbuf = (f16*)(ws + offW);
  int2* meta = (int2*)(ws + offM);

  fused_pre<<<1392, 256, 0, stream>>>(fmap1, fmap2, coords, A, Bc, meta);
  corr_gemm<<<1088, 256, 0, stream>>>(A, Bc, meta, Wbuf);
  corr_sample<<<dim3(288, 1, 4), 256, 0, stream>>>(Wbuf, coords, out);
}

// Round 9
// 129.901 us; speedup vs baseline: 1.1366x; 1.1366x over previous
//
#include <hip/hip_runtime.h>
#include <stdint.h>

typedef _Float16 f16;
typedef __attribute__((ext_vector_type(4))) _Float16 f16x4;
typedef __attribute__((ext_vector_type(8))) _Float16 f16x8;
typedef __attribute__((ext_vector_type(4))) float f32x4;
typedef __attribute__((ext_vector_type(2))) float fv2;
typedef __attribute__((ext_vector_type(4))) float fv4;

#define H0 64
#define W0 128
#define NPIX 8192   // H0*W0
#define KD 256
#define NCAT 10880  // 8192 + 2048 + 512 + 128
#define OFF1 8192
#define OFF2 10240
#define OFF3 10752

// Fragment-native operand layout: X[kk][row][32] (kk = K/32 chunk).
// A 16-lane quarter-wave frag load (row=lr, octet=ko) is then one contiguous
// 1 KB global_load_dwordx4 per 16-row group -> perfectly coalesced from L2.

// ---------------------------------------------------------------------------
// 1) fused pre-pass: transpose+cvt both fmaps into frag layout, pooled
//    feature rows (read fp32 input directly), window metadata.
//    grid = 512 + 512 + 336 + 32 = 1392
// ---------------------------------------------------------------------------
__global__ __launch_bounds__(256) void fused_pre(const float* __restrict__ in0,
                                                 const float* __restrict__ in1,
                                                 const float* __restrict__ coords,
                                                 f16* __restrict__ At,
                                                 f16* __restrict__ Bt,
                                                 int2* __restrict__ meta) {
  __shared__ f16 tile[64][65];
  int bid = blockIdx.x;
  int t = threadIdx.x;

  if (bid < 1024) {                       // ---- transpose + cvt ----
    const float* in = (bid < 512) ? in0 : in1;
    f16* out = (bid < 512) ? At : Bt;
    size_t NR = (bid < 512) ? NPIX : NCAT;
    int bx = bid & 511;
    int m0 = (bx & 127) * 64;
    int d0 = (bx >> 7) * 64;
    int a = t & 63, b = t >> 6;
#pragma unroll
    for (int i = 0; i < 16; ++i) {
      int d = b + i * 4;
      tile[a][d] = (f16)in[(size_t)(d0 + d) * NPIX + m0 + a];
    }
    __syncthreads();
#pragma unroll
    for (int i = 0; i < 16; ++i) {
      int m = b + i * 4;
      int d = d0 + a;
      out[((size_t)(d >> 5) * NR + (m0 + m)) * 32 + (d & 31)] = tile[m][a];
    }
  } else if (bid < 1360) {                // ---- pooled feature rows ----
    int idx = (bid - 1024) * 256 + t;     // 0..86015
    float acc[8] = {0, 0, 0, 0, 0, 0, 0, 0};
    int r, dc;
    if (idx < 65536) {                    // lev1: 2048 rows, 2x2
      int r1 = idx & 2047; dc = idx >> 11; r = r1;
      int y = r1 >> 6, x = r1 & 63;
#pragma unroll
      for (int e = 0; e < 8; ++e) {
        const float* p = in1 + (size_t)(dc * 8 + e) * NPIX + (y * 2) * W0 + x * 2;
        fv2 s0 = *(const fv2*)p;
        fv2 s1 = *(const fv2*)(p + W0);
        acc[e] = (s0[0] + s0[1] + s1[0] + s1[1]) * 0.25f;
      }
    } else if (idx < 81920) {             // lev2: 512 rows, 4x4
      int i2 = idx - 65536;
      int r2 = i2 & 511; dc = i2 >> 9; r = 2048 + r2;
      int y = r2 >> 5, x = r2 & 31;
#pragma unroll
      for (int e = 0; e < 8; ++e) {
        const float* p = in1 + (size_t)(dc * 8 + e) * NPIX + (y * 4) * W0 + x * 4;
        float s = 0.f;
#pragma unroll
        for (int h = 0; h < 4; ++h) {
          fv4 v = *(const fv4*)(p + h * W0);
          s += v[0] + v[1] + v[2] + v[3];
        }
        acc[e] = s * 0.0625f;
      }
    } else {                              // lev3: 128 rows, 8x8
      int i3 = idx - 81920;
      int r3 = i3 & 127; dc = i3 >> 7; r = 2560 + r3;
      int y = r3 >> 4, x = r3 & 15;
#pragma unroll
      for (int e = 0; e < 8; ++e) {
        const float* p = in1 + (size_t)(dc * 8 + e) * NPIX + (y * 8) * W0 + x * 8;
        float s = 0.f;
#pragma unroll
        for (int h = 0; h < 8; ++h) {
          fv4 v0 = *(const fv4*)(p + h * W0);
          fv4 v1 = *(const fv4*)(p + h * W0 + 4);
          s += v0[0] + v0[1] + v0[2] + v0[3] + v1[0] + v1[1] + v1[2] + v1[3];
        }
        acc[e] = s * 0.015625f;
      }
    }
    f16x8 o;
#pragma unroll
    for (int e = 0; e < 8; ++e) o[e] = (f16)acc[e];
    *(f16x8*)(Bt + ((size_t)(dc >> 2) * NCAT + 8192 + r) * 32 + (dc & 3) * 8) = o;
  } else {                                // ---- window metadata ----
    int m = (bid - 1360) * 256 + t;
    float cx = coords[m];
    float cy = coords[NPIX + m];
    int mx = 0, my = 0;
#pragma unroll
    for (int lev = 0; lev < 4; ++lev) {
      float inv = 1.0f / (float)(1 << lev);
      int X0 = (int)floorf(cx * inv) - 4;   // identical expr in corr_sample
      int Y0 = (int)floorf(cy * inv) - 4;
      mx |= (X0 & 0xff) << (8 * lev);
      my |= (Y0 & 0xff) << (8 * lev);
    }
    meta[m] = make_int2(mx, my);
  }
}

// ---------------------------------------------------------------------------
// 2) GEMM, barrier-free: no LDS, no inline asm. Operands are L2-resident in
//    fragment layout; each wave loads its MFMA frags straight to registers
//    (coalesced 1KB/instr), software-pipelined 2 deep; compiler inserts
//    counted vmcnt. Block = 4 waves, 256x128 tile (wave = 64 rows x 128 cols,
//    B-frags shared by all 4 waves -> L1 hits). XCD-local bm swizzle.
//    Compact-window scatter epilogue (early-out) -> Wbuf.
// ---------------------------------------------------------------------------
__global__ __launch_bounds__(256, 2) void corr_gemm(const f16* __restrict__ At,
                                                    const f16* __restrict__ Bt,
                                                    const int2* __restrict__ meta,
                                                    f16* __restrict__ Wbuf) {
  int bid = blockIdx.x;        // 2720 = 8 xcd * 4 bmt * 85 bn
  int bm = (((bid & 7) << 2) | ((bid >> 3) & 3)) << 8;   // XCD-local A set 512KB
  int bn = (bid >> 5) << 7;

  int t = threadIdx.x;
  int lane = t & 63;
  int w = t >> 6;              // wave 0..3: rows [bm+w*64, +64)
  int lr = lane & 15;
  int ko = lane >> 4;

  const f16* Ab = At + (size_t)(bm + w * 64 + lr) * 32 + ko * 8;
  const f16* Bb = Bt + (size_t)(bn + lr) * 32 + ko * 8;

  f16x8 af[2][4], bf[2][8];
#define LOADK(s, kk)                                                           \
  do {                                                                         \
    const f16* ap = Ab + (size_t)(kk) * (NPIX * 32);                           \
    const f16* bp = Bb + (size_t)(kk) * (NCAT * 32);                           \
    _Pragma("unroll")                                                          \
    for (int i = 0; i < 4; ++i) af[s][i] = *(const f16x8*)(ap + i * 512);      \
    _Pragma("unroll")                                                          \
    for (int i = 0; i < 8; ++i) bf[s][i] = *(const f16x8*)(bp + i * 512);      \
  } while (0)

  f32x4 acc[4][8];
#pragma unroll
  for (int i = 0; i < 4; ++i)
#pragma unroll
    for (int j = 0; j < 8; ++j) acc[i][j] = (f32x4){0.f, 0.f, 0.f, 0.f};

  LOADK(0, 0);
  LOADK(1, 1);

#pragma unroll
  for (int kk = 0; kk < 8; ++kk) {
    const int cur = kk & 1;
#pragma unroll
    for (int mi = 0; mi < 4; ++mi)
#pragma unroll
      for (int ni = 0; ni < 8; ++ni)
        acc[mi][ni] = __builtin_amdgcn_mfma_f32_16x16x32_f16(
            af[cur][mi], bf[cur][ni], acc[mi][ni], 0, 0, 0);
    if (kk + 2 < 8) LOADK(cur, kk + 2);   // refill set just consumed
  }
#undef LOADK

  // ---- compact-window scatter epilogue (tile = single level) ----
  int lev, n0, wlog;
  if (bn < OFF1)      { lev = 0; n0 = bn;        wlog = 7; }
  else if (bn < OFF2) { lev = 1; n0 = bn - OFF1; wlog = 6; }
  else if (bn < OFF3) { lev = 2; n0 = bn - OFF2; wlog = 5; }
  else                { lev = 3; n0 = bn - OFF3; wlog = 4; }
  int wmask = (1 << wlog) - 1;
  int yA = n0 >> wlog;
  int yB = (n0 + 127) >> wlog;
  int ycol[8], xcol[8];
#pragma unroll
  for (int ni = 0; ni < 8; ++ni) {
    int n = n0 + ni * 16 + lr;
    ycol[ni] = n >> wlog;
    xcol[ni] = n & wmask;
  }
  f16* wlev = Wbuf + (size_t)(lev * 100) * NPIX;
  int sh = lev * 8;
#pragma unroll
  for (int mi = 0; mi < 4; ++mi)
#pragma unroll
    for (int r2 = 0; r2 < 4; ++r2) {
      int grow = bm + w * 64 + mi * 16 + ko * 4 + r2;
      int2 mv = meta[grow];
      int Y0 = (int)(signed char)((mv.y >> sh) & 0xff);
      if (Y0 <= yB && Y0 + 9 >= yA) {
        int X0 = (int)(signed char)((mv.x >> sh) & 0xff);
        f16* rowp = wlev + grow;
#pragma unroll
        for (int ni = 0; ni < 8; ++ni) {
          int dy = ycol[ni] - Y0;
          int dx = xcol[ni] - X0;
          if ((unsigned)dy < 10u && (unsigned)dx < 10u)
            rowp[(size_t)(dy * 10 + dx) * NPIX] =
                (f16)(acc[mi][ni][r2] * 0.0625f);
        }
      }
    }
}

// ---------------------------------------------------------------------------
// 3) bilinear sampling from compact corner buffer W[lev*100+dy*10+dx][m].
// ---------------------------------------------------------------------------
__global__ __launch_bounds__(256) void corr_sample(const f16* __restrict__ Wbuf,
                                                   const float* __restrict__ coords,
                                                   float* __restrict__ out) {
  int bx = blockIdx.x;            // 288 = 8 xcd * 36
  int xcd = bx & 7;
  int idx = bx >> 3;              // 0..35
  int j = idx % 9;                // window row
  int mc = xcd + 8 * (idx / 9);   // m-chunk 0..31
  int m = mc * 256 + threadIdx.x;
  int lev = blockIdx.z;
  int Hl = H0 >> lev, Wl = W0 >> lev;

  float cx = coords[m];
  float cy = coords[NPIX + m];
  float inv = 1.0f / (float)(1 << lev);
  float xb = cx * inv, yb = cy * inv;
  float fx = floorf(xb), fy = floorf(yb);
  int X0 = (int)fx - 4, Y0 = (int)fy - 4;   // matches fused_pre meta exactly
  float wx1 = xb - fx, wx0 = 1.0f - wx1;
  float wy1 = yb - fy, wy0 = 1.0f - wy1;

  const f16* wb = Wbuf + (size_t)(lev * 100) * NPIX + m;
  float* op = out + ((size_t)lev * 81 + (size_t)j * 9) * NPIX + m;

  float cur[10], nxt[10];
  auto loadrow = [&](float* row, int jr) {
    int y = Y0 + jr;
    bool yin = (unsigned)y < (unsigned)Hl;
#pragma unroll
    for (int i = 0; i < 10; ++i) {
      int x = X0 + i;
      bool in = yin && ((unsigned)x < (unsigned)Wl);
      row[i] = in ? (float)wb[(size_t)(jr * 10 + i) * NPIX] : 0.0f;
    }
  };
  loadrow(cur, j);
  loadrow(nxt, j + 1);
#pragma unroll
  for (int i = 0; i < 9; ++i) {
    float v = wy0 * (wx0 * cur[i] + wx1 * cur[i + 1])
            + wy1 * (wx0 * nxt[i] + wx1 * nxt[i + 1]);
    op[(size_t)i * NPIX] = v;
  }
}

// ---------------------------------------------------------------------------
extern "C" void kernel_launch(void* const* d_in, const int* in_sizes, int n_in,
                              void* d_out, int out_size, void* d_ws, size_t ws_size,
                              hipStream_t stream) {
  const float* fmap1  = (const float*)d_in[0];   // [1,256,64,128]
  const float* fmap2  = (const float*)d_in[1];
  const float* coords = (const float*)d_in[2];   // [1,2,64,128]
  float* out = (float*)d_out;                    // [1,324,64,128] fp32

  char* ws = (char*)d_ws;
  size_t offA = 0;
  size_t offB = offA + (size_t)NPIX * KD * 2;    // At: 4 MB
  size_t offW = offB + (size_t)NCAT * KD * 2;    // Bt: 5.44 MB
  size_t offM = offW + (size_t)400 * NPIX * 2;   // W: 6.55 MB
  size_t need = offM + (size_t)NPIX * 8;         // meta: 64 KB => ~16.1 MB
  if (ws_size < need) return;

  f16*  At   = (f16*)(ws + offA);
  f16*  Bt   = (f16*)(ws + offB);
  f16*  Wbuf = (f16*)(ws + offW);
  int2* meta = (int2*)(ws + offM);

  fused_pre<<<1392, 256, 0, stream>>>(fmap1, fmap2, coords, At, Bt, meta);
  corr_gemm<<<2720, 256, 0, stream>>>(At, Bt, meta, Wbuf);
  corr_sample<<<dim3(288, 1, 4), 256, 0, stream>>>(Wbuf, coords, out);
}